// Round 2
// baseline (5738.342 us; speedup 1.0000x reference)
//
#include <hip/hip_runtime.h>

#define BB 64
#define LL 32
#define DD 512
#define HH 1024
#define GG 4096   // 4*H
#define VV 32000
#define EHH 512
#define ELL 40

// ws layout (float units)
#define OFF_H   0                        // hstates: [33][64][1024]  (index 0 = hx0)
#define OFF_C   (33*BB*HH)               // cx: [64][1024]
#define OFF_GX  (OFF_C + BB*HH)          // gates_x: [32][64][4096]
#define OFF_AM  (OFF_GX + LL*BB*GG)      // amax: 2048 u64 (=4096 floats)
#define OFF_W4  (OFF_AM + 4096)          // W4: [256][4096][4] = 16 MB

__device__ __forceinline__ unsigned long long packkey(float v, int n) {
    unsigned u = __float_as_uint(v);
    u = (u & 0x80000000u) ? ~u : (u | 0x80000000u);
    return ((unsigned long long)u << 32) | (unsigned)(0x7FFFFFFF - n);
}

// ---- hx0 = hidden_state[:, -1, :] @ W_p.T + b_p ; cx = 0 ; amax = 0 ----
__global__ __launch_bounds__(128) void init_kernel(
    const float* __restrict__ hid, const float* __restrict__ Wp,
    const float* __restrict__ bp, float* __restrict__ h0,
    float* __restrict__ cx, unsigned long long* __restrict__ amax)
{
    int b = blockIdx.x;
    int h = blockIdx.y * 128 + threadIdx.x;
    const float4* hrow = (const float4*)(hid + ((size_t)b*ELL + (ELL-1))*EHH);
    const float4* wrow = (const float4*)(Wp + (size_t)h*EHH);
    float acc = 0.f;
    #pragma unroll 4
    for (int k = 0; k < EHH/4; ++k) {
        float4 a = hrow[k], w = wrow[k];
        acc += a.x*w.x + a.y*w.y + a.z*w.z + a.w*w.w;
    }
    h0[b*HH + h] = acc + bp[h];
    cx[b*HH + h] = 0.f;
    int tg = (b*8 + blockIdx.y)*128 + threadIdx.x;
    if (tg < LL*BB) amax[tg] = 0ULL;
}

// ---- W4[(k4*4096 + c)*4 + j] = Whh[c][4*k4 + j]  (k-major transposed W_hh) ----
__global__ __launch_bounds__(256) void transpose_whh(
    const float* __restrict__ Whh, float* __restrict__ W4)
{
    __shared__ float T[64][65];
    const int c0 = blockIdx.x * 64;   // 4096/64 = 64
    const int k0 = blockIdx.y * 64;   // 1024/64 = 16
    const int tid = threadIdx.x;
    #pragma unroll
    for (int p = 0; p < 4; ++p) {
        int r  = p*16 + (tid >> 4);
        int kk = (tid & 15) * 4;
        float4 v = *(const float4*)(Whh + (size_t)(c0 + r)*HH + k0 + kk);
        T[r][kk+0] = v.x; T[r][kk+1] = v.y; T[r][kk+2] = v.z; T[r][kk+3] = v.w;
    }
    __syncthreads();
    #pragma unroll
    for (int p = 0; p < 4; ++p) {
        int k4l = p*4 + (tid >> 6);
        int cl  = tid & 63;
        int k4  = (k0 >> 2) + k4l;
        float4 v;
        v.x = T[cl][k4l*4+0]; v.y = T[cl][k4l*4+1];
        v.z = T[cl][k4l*4+2]; v.w = T[cl][k4l*4+3];
        *(float4*)(W4 + ((size_t)k4*GG + c0 + cl)*4) = v;
    }
}

// ================= 128x128 fp32 GEMM building blocks =================
// 256 threads, 8x8 outputs/thread; rows {ty*4..+3, 64+ty*4..+3}, cols likewise on tx.
#define BKK 16

// ---- gates_x[r][n] = sent[b][l][:] . W_ih[n][:] + b_ih[n] + b_hh[n],  r=l*64+b ----
__global__ __launch_bounds__(256) void gates_x_kernel(
    const float* __restrict__ sent, const float* __restrict__ Wih,
    const float* __restrict__ bih, const float* __restrict__ bhh,
    float* __restrict__ gx)
{
    __shared__ float As[BKK][132];
    __shared__ float Bs[BKK][132];
    const int m0 = blockIdx.x * 128;
    const int n0 = blockIdx.y * 128;
    const int tid = threadIdx.x;
    const int tx = tid & 15, ty = tid >> 4;
    const int srow = tid >> 1;
    const int skb  = (tid & 1) * 8;
    float acc[8][8] = {};
    const int gr = m0 + srow;
    const float* arow = sent + ((size_t)(gr & 63)*LL + (gr >> 6))*DD;
    const float* brow = Wih + (size_t)(n0 + srow)*DD;
    for (int k0 = 0; k0 < DD; k0 += BKK) {
        float4 a0 = *(const float4*)(arow + k0 + skb);
        float4 a1 = *(const float4*)(arow + k0 + skb + 4);
        float4 b0 = *(const float4*)(brow + k0 + skb);
        float4 b1 = *(const float4*)(brow + k0 + skb + 4);
        As[skb+0][srow]=a0.x; As[skb+1][srow]=a0.y; As[skb+2][srow]=a0.z; As[skb+3][srow]=a0.w;
        As[skb+4][srow]=a1.x; As[skb+5][srow]=a1.y; As[skb+6][srow]=a1.z; As[skb+7][srow]=a1.w;
        Bs[skb+0][srow]=b0.x; Bs[skb+1][srow]=b0.y; Bs[skb+2][srow]=b0.z; Bs[skb+3][srow]=b0.w;
        Bs[skb+4][srow]=b1.x; Bs[skb+5][srow]=b1.y; Bs[skb+6][srow]=b1.z; Bs[skb+7][srow]=b1.w;
        __syncthreads();
        #pragma unroll
        for (int k = 0; k < BKK; ++k) {
            float4 aL = *(const float4*)&As[k][ty*4];
            float4 aH = *(const float4*)&As[k][64 + ty*4];
            float4 bL = *(const float4*)&Bs[k][tx*4];
            float4 bH = *(const float4*)&Bs[k][64 + tx*4];
            float av[8] = {aL.x,aL.y,aL.z,aL.w,aH.x,aH.y,aH.z,aH.w};
            float bw[8] = {bL.x,bL.y,bL.z,bL.w,bH.x,bH.y,bH.z,bH.w};
            #pragma unroll
            for (int i = 0; i < 8; ++i)
                #pragma unroll
                for (int j = 0; j < 8; ++j)
                    acc[i][j] = fmaf(av[i], bw[j], acc[i][j]);
        }
        __syncthreads();
    }
    float bvv[8];
    #pragma unroll
    for (int j = 0; j < 8; ++j) {
        int cn = (j < 4) ? (tx*4 + j) : (64 + tx*4 + (j-4));
        bvv[j] = bih[n0 + cn] + bhh[n0 + cn];
    }
    #pragma unroll
    for (int i = 0; i < 8; ++i) {
        int rm = (i < 4) ? (ty*4 + i) : (64 + ty*4 + (i-4));
        float* orow = gx + (size_t)(m0 + rm)*GG + n0;
        float4 oL, oH;
        oL.x = acc[i][0]+bvv[0]; oL.y = acc[i][1]+bvv[1]; oL.z = acc[i][2]+bvv[2]; oL.w = acc[i][3]+bvv[3];
        oH.x = acc[i][4]+bvv[4]; oH.y = acc[i][5]+bvv[5]; oH.z = acc[i][6]+bvv[6]; oH.w = acc[i][7]+bvv[7];
        *(float4*)(orow + tx*4) = oL;
        *(float4*)(orow + 64 + tx*4) = oH;
    }
}

// ---- one recurrence step: no LDS in K-loop; W4 coalesced, h via uniform loads ----
__global__ __launch_bounds__(256) void lstm_step_kernel(
    const float* __restrict__ W4,     // [256][4096][4]
    const float* __restrict__ gxs,    // [64][4096] for this step (pre-biased)
    const float* __restrict__ hprev,  // [64][1024]
    float* __restrict__ hnew,         // [64][1024]
    float* __restrict__ cx)           // [64][1024] in-out
{
    const int tid = threadIdx.x;
    const int cb = blockIdx.x;        // 0..15 : h-index block
    const int bg = blockIdx.y;        // 0..7  : batch group (8 batches)
    const int gt = tid >> 6;          // gate 0..3
    const int hl = tid & 63;
    const int hh = cb*64 + hl;        // 0..1023
    const int col = gt*HH + hh;       // 0..4095
    float acc[8] = {};
    const float* wp = W4 + (size_t)col*4;
    const float* hp = hprev + (size_t)bg*8*HH;
    #pragma unroll 4
    for (int k4 = 0; k4 < HH/4; ++k4) {
        float4 w = *(const float4*)(wp + (size_t)k4*(GG*4));
        #pragma unroll
        for (int b = 0; b < 8; ++b) {
            float4 hv = *(const float4*)(hp + b*HH + k4*4);   // block-uniform address
            acc[b] = fmaf(hv.x, w.x, acc[b]);
            acc[b] = fmaf(hv.y, w.y, acc[b]);
            acc[b] = fmaf(hv.z, w.z, acc[b]);
            acc[b] = fmaf(hv.w, w.w, acc[b]);
        }
    }
    __shared__ float sh[4][64][8];
    #pragma unroll
    for (int b = 0; b < 8; ++b)
        sh[gt][hl][b] = acc[b] + gxs[(size_t)(bg*8 + b)*GG + col];
    __syncthreads();
    if (gt == 0) {
        #pragma unroll
        for (int b = 0; b < 8; ++b) {
            int bb = bg*8 + b;
            float gi = sh[0][hl][b], gf = sh[1][hl][b];
            float gg = sh[2][hl][b], go = sh[3][hl][b];
            float si = 1.f/(1.f + expf(-gi));
            float sf = 1.f/(1.f + expf(-gf));
            float so = 1.f/(1.f + expf(-go));
            float cc = cx[(size_t)bb*HH + hh];
            float cn = sf*cc + si*tanhf(gg);
            cx[(size_t)bb*HH + hh] = cn;
            hnew[(size_t)bb*HH + hh] = so*tanhf(cn);
        }
    }
}

// ---- logits = hs_all @ W_v.T + b_v, fused argmax (128x128 tile, 8x8/thread) ----
__global__ __launch_bounds__(256) void logits_kernel(
    const float* __restrict__ A,   // [2048][1024] (hstates rows 64..)
    const float* __restrict__ Wv,  // [32000][1024]
    const float* __restrict__ bv,
    float* __restrict__ out,       // [64][32][32000]
    unsigned long long* __restrict__ amax)
{
    __shared__ union UShared {
        struct { float As[BKK][132]; float Bs[BKK][132]; } t;
        unsigned long long red[128][17];
    } u;
    const int m0 = blockIdx.x * 128;
    const int n0 = blockIdx.y * 128;
    const int tid = threadIdx.x;
    const int tx = tid & 15, ty = tid >> 4;
    const int srow = tid >> 1;
    const int skb  = (tid & 1) * 8;
    float acc[8][8] = {};
    const float* arow = A  + (size_t)(m0 + srow)*HH;
    const float* brow = Wv + (size_t)(n0 + srow)*HH;
    for (int k0 = 0; k0 < HH; k0 += BKK) {
        float4 a0 = *(const float4*)(arow + k0 + skb);
        float4 a1 = *(const float4*)(arow + k0 + skb + 4);
        float4 b0 = *(const float4*)(brow + k0 + skb);
        float4 b1 = *(const float4*)(brow + k0 + skb + 4);
        u.t.As[skb+0][srow]=a0.x; u.t.As[skb+1][srow]=a0.y; u.t.As[skb+2][srow]=a0.z; u.t.As[skb+3][srow]=a0.w;
        u.t.As[skb+4][srow]=a1.x; u.t.As[skb+5][srow]=a1.y; u.t.As[skb+6][srow]=a1.z; u.t.As[skb+7][srow]=a1.w;
        u.t.Bs[skb+0][srow]=b0.x; u.t.Bs[skb+1][srow]=b0.y; u.t.Bs[skb+2][srow]=b0.z; u.t.Bs[skb+3][srow]=b0.w;
        u.t.Bs[skb+4][srow]=b1.x; u.t.Bs[skb+5][srow]=b1.y; u.t.Bs[skb+6][srow]=b1.z; u.t.Bs[skb+7][srow]=b1.w;
        __syncthreads();
        #pragma unroll
        for (int k = 0; k < BKK; ++k) {
            float4 aL = *(const float4*)&u.t.As[k][ty*4];
            float4 aH = *(const float4*)&u.t.As[k][64 + ty*4];
            float4 bL = *(const float4*)&u.t.Bs[k][tx*4];
            float4 bH = *(const float4*)&u.t.Bs[k][64 + tx*4];
            float av[8] = {aL.x,aL.y,aL.z,aL.w,aH.x,aH.y,aH.z,aH.w};
            float bw[8] = {bL.x,bL.y,bL.z,bL.w,bH.x,bH.y,bH.z,bH.w};
            #pragma unroll
            for (int i = 0; i < 8; ++i)
                #pragma unroll
                for (int j = 0; j < 8; ++j)
                    acc[i][j] = fmaf(av[i], bw[j], acc[i][j]);
        }
        __syncthreads();
    }
    int cn[8];
    float bvv[8];
    #pragma unroll
    for (int j = 0; j < 8; ++j) {
        cn[j] = (j < 4) ? (tx*4 + j) : (64 + tx*4 + (j-4));
        bvv[j] = bv[n0 + cn[j]];
    }
    unsigned long long rowbest[8];
    int rms[8];
    #pragma unroll
    for (int i = 0; i < 8; ++i) {
        int rm = (i < 4) ? (ty*4 + i) : (64 + ty*4 + (i-4));
        rms[i] = rm;
        int r = m0 + rm;
        int b = r & 63, l = r >> 6;
        float o[8];
        #pragma unroll
        for (int j = 0; j < 8; ++j) o[j] = acc[i][j] + bvv[j];
        float* orow = out + ((size_t)(b*LL + l))*VV + n0;
        float4 oL, oH;
        oL.x=o[0]; oL.y=o[1]; oL.z=o[2]; oL.w=o[3];
        oH.x=o[4]; oH.y=o[5]; oH.z=o[6]; oH.w=o[7];
        *(float4*)(orow + tx*4) = oL;
        *(float4*)(orow + 64 + tx*4) = oH;
        unsigned long long best = packkey(o[0], n0 + cn[0]);
        #pragma unroll
        for (int j = 1; j < 8; ++j) {
            unsigned long long k1 = packkey(o[j], n0 + cn[j]);
            if (k1 > best) best = k1;
        }
        rowbest[i] = best;
    }
    // safe: all As/Bs reads completed before the loop-final __syncthreads
    #pragma unroll
    for (int i = 0; i < 8; ++i) u.red[rms[i]][tx] = rowbest[i];
    __syncthreads();
    if (tid < 128) {
        unsigned long long bb2 = u.red[tid][0];
        #pragma unroll
        for (int j = 1; j < 16; ++j) {
            unsigned long long v = u.red[tid][j];
            if (v > bb2) bb2 = v;
        }
        atomicMax(&amax[m0 + tid], bb2);
    }
}

__global__ __launch_bounds__(256) void finalize_kernel(
    const unsigned long long* __restrict__ amax, float* __restrict__ outp)
{
    int r = blockIdx.x * 256 + threadIdx.x;
    if (r < LL*BB) {
        unsigned n = 0x7FFFFFFFu - (unsigned)(amax[r] & 0xFFFFFFFFu);
        int b = r & 63, l = r >> 6;
        outp[b*LL + l] = (float)n;
    }
}

extern "C" void kernel_launch(void* const* d_in, const int* in_sizes, int n_in,
                              void* d_out, int out_size, void* d_ws, size_t ws_size,
                              hipStream_t stream) {
    (void)in_sizes; (void)n_in; (void)out_size; (void)ws_size;
    const float* sent = (const float*)d_in[0];
    const float* hid  = (const float*)d_in[1];
    const float* Wih  = (const float*)d_in[2];
    const float* Whh  = (const float*)d_in[3];
    const float* bih  = (const float*)d_in[4];
    const float* bhh  = (const float*)d_in[5];
    const float* Wp   = (const float*)d_in[6];
    const float* bp   = (const float*)d_in[7];
    const float* Wv   = (const float*)d_in[8];
    const float* bv   = (const float*)d_in[9];
    float* out = (float*)d_out;

    float* ws = (float*)d_ws;
    float* hst = ws + OFF_H;                 // [33][64][1024]
    float* cx  = ws + OFF_C;
    float* gx  = ws + OFF_GX;                // [32][64][4096]
    unsigned long long* amax = (unsigned long long*)(ws + OFF_AM);
    float* W4  = ws + OFF_W4;                // [256][4096][4]

    transpose_whh<<<dim3(GG/64, HH/64), 256, 0, stream>>>(Whh, W4);
    init_kernel<<<dim3(BB, 8), 128, 0, stream>>>(hid, Wp, bp, hst, cx, amax);
    gates_x_kernel<<<dim3(2048/128, GG/128), 256, 0, stream>>>(sent, Wih, bih, bhh, gx);
    for (int s = 1; s <= LL; ++s) {
        lstm_step_kernel<<<dim3(16, 8), 256, 0, stream>>>(
            W4, gx + (size_t)(s-1)*BB*GG,
            hst + (size_t)(s-1)*BB*HH, hst + (size_t)s*BB*HH, cx);
    }
    logits_kernel<<<dim3(2048/128, VV/128), 256, 0, stream>>>(
        hst + (size_t)BB*HH, Wv, bv, out, amax);
    finalize_kernel<<<dim3((LL*BB + 255)/256), 256, 0, stream>>>(
        amax, out + (size_t)BB*LL*VV);
}